// Round 10
// baseline (523.960 us; speedup 1.0000x reference)
//
#include <hip/hip_runtime.h>

#define NLEVELS 16
#define HSIZE (1u << 19)
#define HMASK ((1u << 19) - 1u)
#define P2 73856093u
#define P3 19349663u

// clang-native vectors (accepted by __builtin_nontemporal_*, unlike HIP types)
typedef float nf4 __attribute__((ext_vector_type(4)));
typedef float nf2 __attribute__((ext_vector_type(2)));

// res[L] = floor(16 * (2^(1/3))^L)
__constant__ int c_res[NLEVELS] = {16, 20, 25, 32, 40, 50, 64, 80,
                                   101, 128, 161, 203, 256, 322, 406, 512};

// ---------------------------------------------------------------------------
// Kernel A (r8): level-major, XCD affinity, TWO points per thread with all
// EIGHT paired-corner gathers in flight per thread. r7 showed the 4 gathers
// of the 1-pt version were already parallel (VGPR 20 = 16 dst + 4 addr) and
// time was unchanged by keep-alive -> this build discriminates between
// "L2 request-service ceiling" (time flat) and "per-wave latency/issue bound"
// (time drops up to ~1.5x). Block = 512 points; chunk = 512.
// All 8 hashes computed before any load; keep-alive pins all 8 destinations.
// ---------------------------------------------------------------------------
template <bool TO_WS>
__global__ __launch_bounds__(256) void hashgrid_kernel(
    const float* __restrict__ positions,  // [npoints, 3]
    const float* __restrict__ tables,     // [16, 2^19, 2]
    float2* __restrict__ dst,             // TO_WS: tiled ws; else out [npoints][16]
    int npoints)
{
    int nch = (npoints + 511) >> 9;       // 512-point chunks
    int b = blockIdx.x;
    int L, chunk;
    if (TO_WS) {
        int xcd = b & 7;
        int j = b >> 3;                   // [0, 2*nch)
        L = xcd + ((j >= nch) ? 8 : 0);
        chunk = (j >= nch) ? (j - nch) : j;
    } else {
        L = b / nch;
        chunk = b - L * nch;
    }
    int t = threadIdx.x;
    int p0 = (chunk << 9) + (t << 1);     // even point index
    if (p0 >= npoints) return;
    bool haveB = (p0 + 1 < npoints);

    // 6 floats for 2 points = 3 aligned float2 loads (byte offset 12*p0, p0 even)
    const float2* pos2 = (const float2*)positions + ((size_t)chunk * 768 + 3 * t);
    float2 f01 = pos2[0];
    float2 f23 = pos2[1];
    float2 f45 = haveB ? pos2[2] : make_float2(f01.x, f01.y);

    float pAx = (f01.x + 1.0f) * 0.5f, pAy = (f01.y + 1.0f) * 0.5f, pAz = (f23.x + 1.0f) * 0.5f;
    float pBx = (f23.y + 1.0f) * 0.5f, pBy = (f45.x + 1.0f) * 0.5f, pBz = (f45.y + 1.0f) * 0.5f;
    if (!haveB) { pBx = pAx; pBy = pAy; pBz = pAz; }   // harmless duplicate

    float rm1 = (float)(c_res[L] - 1);

    // --- point A indices ---
    float sAx = pAx * rm1, sAy = pAy * rm1, sAz = pAz * rm1;
    float bAx = floorf(sAx), bAy = floorf(sAy), bAz = floorf(sAz);
    float fAx = sAx - bAx, fAy = sAy - bAy, fAz = sAz - bAz;
    unsigned sA = (unsigned)(int)bAx + (unsigned)(int)bAy * P2 + (unsigned)(int)bAz * P3;
    unsigned hA0 = sA & HMASK,             hA1 = (sA + P2) & HMASK;
    unsigned hA2 = (sA + P3) & HMASK,      hA3 = (sA + P2 + P3) & HMASK;

    // --- point B indices ---
    float sBx = pBx * rm1, sBy = pBy * rm1, sBz = pBz * rm1;
    float bBx = floorf(sBx), bBy = floorf(sBy), bBz = floorf(sBz);
    float fBx = sBx - bBx, fBy = sBy - bBy, fBz = sBz - bBz;
    unsigned sB = (unsigned)(int)bBx + (unsigned)(int)bBy * P2 + (unsigned)(int)bBz * P3;
    unsigned hB0 = sB & HMASK,             hB1 = (sB + P2) & HMASK;
    unsigned hB2 = (sB + P3) & HMASK,      hB3 = (sB + P2 + P3) & HMASK;

    const float* tabf = tables + (size_t)L * (2u * HSIZE);

    unsigned wA0 = (hA0 == HMASK) ? 1u : 0u, wA1 = (hA1 == HMASK) ? 1u : 0u;
    unsigned wA2 = (hA2 == HMASK) ? 1u : 0u, wA3 = (hA3 == HMASK) ? 1u : 0u;
    unsigned wB0 = (hB0 == HMASK) ? 1u : 0u, wB1 = (hB1 == HMASK) ? 1u : 0u;
    unsigned wB2 = (hB2 == HMASK) ? 1u : 0u, wB3 = (hB3 == HMASK) ? 1u : 0u;

    // Issue ALL EIGHT 16B paired loads, then pin all destinations live.
    nf4 g0 = *(const nf4*)(tabf + 2u * (hA0 - wA0));
    nf4 g1 = *(const nf4*)(tabf + 2u * (hA1 - wA1));
    nf4 g2 = *(const nf4*)(tabf + 2u * (hA2 - wA2));
    nf4 g3 = *(const nf4*)(tabf + 2u * (hA3 - wA3));
    nf4 g4 = *(const nf4*)(tabf + 2u * (hB0 - wB0));
    nf4 g5 = *(const nf4*)(tabf + 2u * (hB1 - wB1));
    nf4 g6 = *(const nf4*)(tabf + 2u * (hB2 - wB2));
    nf4 g7 = *(const nf4*)(tabf + 2u * (hB3 - wB3));
    asm volatile("" :: "v"(g0), "v"(g1), "v"(g2), "v"(g3),
                       "v"(g4), "v"(g5), "v"(g6), "v"(g7));

    float2 t0 = ((const float2*)tabf)[0];      // wave-uniform wrap partner

    // lo corner = entry h, hi corner = entry (h+1)&HMASK
    float lx, ly, hx, hy;
    float wx0, wy0, wz0, c0, c1, c2, c3;

    // ---- interpolate point A ----
    wx0 = 1.0f - fAx; wy0 = 1.0f - fAy; wz0 = 1.0f - fAz;
    c0 = wy0 * wz0; c1 = fAy * wz0; c2 = wy0 * fAz; c3 = fAy * fAz;
    float oA0 = 0.0f, oA1 = 0.0f;
    lx = wA0 ? g0.z : g0.x; ly = wA0 ? g0.w : g0.y;
    hx = wA0 ? t0.x : g0.z; hy = wA0 ? t0.y : g0.w;
    oA0 += c0 * (wx0 * lx + fAx * hx); oA1 += c0 * (wx0 * ly + fAx * hy);
    lx = wA1 ? g1.z : g1.x; ly = wA1 ? g1.w : g1.y;
    hx = wA1 ? t0.x : g1.z; hy = wA1 ? t0.y : g1.w;
    oA0 += c1 * (wx0 * lx + fAx * hx); oA1 += c1 * (wx0 * ly + fAx * hy);
    lx = wA2 ? g2.z : g2.x; ly = wA2 ? g2.w : g2.y;
    hx = wA2 ? t0.x : g2.z; hy = wA2 ? t0.y : g2.w;
    oA0 += c2 * (wx0 * lx + fAx * hx); oA1 += c2 * (wx0 * ly + fAx * hy);
    lx = wA3 ? g3.z : g3.x; ly = wA3 ? g3.w : g3.y;
    hx = wA3 ? t0.x : g3.z; hy = wA3 ? t0.y : g3.w;
    oA0 += c3 * (wx0 * lx + fAx * hx); oA1 += c3 * (wx0 * ly + fAx * hy);

    // ---- interpolate point B ----
    wx0 = 1.0f - fBx; wy0 = 1.0f - fBy; wz0 = 1.0f - fBz;
    c0 = wy0 * wz0; c1 = fBy * wz0; c2 = wy0 * fBz; c3 = fBy * fBz;
    float oB0 = 0.0f, oB1 = 0.0f;
    lx = wB0 ? g4.z : g4.x; ly = wB0 ? g4.w : g4.y;
    hx = wB0 ? t0.x : g4.z; hy = wB0 ? t0.y : g4.w;
    oB0 += c0 * (wx0 * lx + fBx * hx); oB1 += c0 * (wx0 * ly + fBx * hy);
    lx = wB1 ? g5.z : g5.x; ly = wB1 ? g5.w : g5.y;
    hx = wB1 ? t0.x : g5.z; hy = wB1 ? t0.y : g5.w;
    oB0 += c1 * (wx0 * lx + fBx * hx); oB1 += c1 * (wx0 * ly + fBx * hy);
    lx = wB2 ? g6.z : g6.x; ly = wB2 ? g6.w : g6.y;
    hx = wB2 ? t0.x : g6.z; hy = wB2 ? t0.y : g6.w;
    oB0 += c2 * (wx0 * lx + fBx * hx); oB1 += c2 * (wx0 * ly + fBx * hy);
    lx = wB3 ? g7.z : g7.x; ly = wB3 ? g7.w : g7.y;
    hx = wB3 ? t0.x : g7.z; hy = wB3 ? t0.y : g7.w;
    oB0 += c3 * (wx0 * lx + fBx * hx); oB1 += c3 * (wx0 * ly + fBx * hy);

    if (TO_WS) {
        // ws layout: [chunk512][16][512] float2 -> per (chunk,L) row = 256 nf4;
        // thread t stores points {2t, 2t+1} as ONE 16B nt store, coalesced.
        nf4 v = {oA0, oA1, oB0, oB1};
        __builtin_nontemporal_store(
            v, (nf4*)dst + ((size_t)chunk * NLEVELS + L) * 256 + t);
    } else {
        dst[(size_t)p0 * NLEVELS + L] = make_float2(oA0, oA1);
        if (haveB) dst[(size_t)(p0 + 1) * NLEVELS + L] = make_float2(oB0, oB1);
    }
}

// ---------------------------------------------------------------------------
// Kernel B (r8): same proven 256-point/34KB tile transpose as r5; only the
// input addressing adapts to the [chunk512][16][512]f2 ws layout.
// Block cb handles half-chunk h = cb&1 of chunk cb>>1.
// ---------------------------------------------------------------------------
__global__ __launch_bounds__(256) void transpose_kernel(
    const nf4* __restrict__ ws4,
    nf4* __restrict__ out4,
    int npoints)
{
    __shared__ float2 lds[256][NLEVELS + 1];
    int cb = blockIdx.x;            // 256-point tile index
    int t = threadIdx.x;
    int chunk = cb >> 1, h = cb & 1;
    // nf4 base of this half-chunk's level rows: chunk*4096 + h*128
    size_t hb = (size_t)chunk * 4096 + (size_t)h * 128;

    nf4 v0 = __builtin_nontemporal_load(&ws4[hb + ((0 * 256 + t) >> 7) * 256 + ((0 * 256 + t) & 127)]);
    nf4 v1 = __builtin_nontemporal_load(&ws4[hb + ((1 * 256 + t) >> 7) * 256 + ((1 * 256 + t) & 127)]);
    nf4 v2 = __builtin_nontemporal_load(&ws4[hb + ((2 * 256 + t) >> 7) * 256 + ((2 * 256 + t) & 127)]);
    nf4 v3 = __builtin_nontemporal_load(&ws4[hb + ((3 * 256 + t) >> 7) * 256 + ((3 * 256 + t) & 127)]);
    nf4 v4 = __builtin_nontemporal_load(&ws4[hb + ((4 * 256 + t) >> 7) * 256 + ((4 * 256 + t) & 127)]);
    nf4 v5 = __builtin_nontemporal_load(&ws4[hb + ((5 * 256 + t) >> 7) * 256 + ((5 * 256 + t) & 127)]);
    nf4 v6 = __builtin_nontemporal_load(&ws4[hb + ((6 * 256 + t) >> 7) * 256 + ((6 * 256 + t) & 127)]);
    nf4 v7 = __builtin_nontemporal_load(&ws4[hb + ((7 * 256 + t) >> 7) * 256 + ((7 * 256 + t) & 127)]);
    asm volatile("" :: "v"(v0), "v"(v1), "v"(v2), "v"(v3),
                       "v"(v4), "v"(v5), "v"(v6), "v"(v7));

    nf4 vv[8] = {v0, v1, v2, v3, v4, v5, v6, v7};
#pragma unroll
    for (int k = 0; k < 8; ++k) {
        int i = (k << 8) + t;                 // i in [0,2048): L = i>>7, m = i&127
        int L = i >> 7;
        int m = i & 127;                      // covers points {2m, 2m+1} of tile
        lds[m][L]       = make_float2(vv[k].x, vv[k].y);   // point 2m   -> row m
        lds[m + 128][L] = make_float2(vv[k].z, vv[k].w);   // point 2m+1 -> row m+128
    }
    __syncthreads();

    size_t base = (size_t)cb * 2048;          // out: 256 points * 8 nf4
#pragma unroll
    for (int k = 0; k < 8; ++k) {
        int i = (k << 8) + t;
        int pp = i >> 3;                      // point within tile
        int q = i & 7;                        // level pair
        int r = (pp >> 1) | ((pp & 1) << 7);  // physical row of point pp
        float2 a = lds[r][2 * q];
        float2 bb = lds[r][2 * q + 1];
        nf4 v = {a.x, a.y, bb.x, bb.y};
        __builtin_nontemporal_store(v, &out4[base + i]);
    }
}

extern "C" void kernel_launch(void* const* d_in, const int* in_sizes, int n_in,
                              void* d_out, int out_size, void* d_ws, size_t ws_size,
                              hipStream_t stream) {
    const float* positions = (const float*)d_in[0];
    const float* tables = (const float*)d_in[1];
    int npoints = in_sizes[0] / 3;                    // 1,048,576
    int nch = (npoints + 511) >> 9;
    int blocks = NLEVELS * nch;                       // 32,768

    size_t ws_needed = (size_t)NLEVELS * npoints * sizeof(float2);  // 128 MiB
    if (ws_size >= ws_needed && (npoints & 511) == 0) {
        float2* ws = (float2*)d_ws;
        hashgrid_kernel<true><<<blocks, 256, 0, stream>>>(positions, tables, ws, npoints);
        transpose_kernel<<<npoints / 256, 256, 0, stream>>>((const nf4*)ws,
                                                            (nf4*)d_out, npoints);
    } else {
        hashgrid_kernel<false><<<blocks, 256, 0, stream>>>(positions, tables,
                                                           (float2*)d_out, npoints);
    }
}

// Round 11
// 507.171 us; speedup vs baseline: 1.0331x; 1.0331x over previous
//
#include <hip/hip_runtime.h>

#define NLEVELS 16
#define HSIZE (1u << 19)
#define HMASK ((1u << 19) - 1u)
#define P2 73856093u
#define P3 19349663u

// clang-native vectors (accepted by __builtin_nontemporal_*, unlike HIP types)
typedef float nf4 __attribute__((ext_vector_type(4)));
typedef float nf2 __attribute__((ext_vector_type(2)));

// res[L] = floor(16 * (2^(1/3))^L)
__constant__ int c_res[NLEVELS] = {16, 20, 25, 32, 40, 50, 64, 80,
                                   101, 128, 161, 203, 256, 322, 406, 512};

// ---------------------------------------------------------------------------
// Kernel A (r11): r7 structure exactly (1 pt/thread, 4 paired-corner 16B
// gathers, XCD affinity, nt ws stores) with ONE change: XCD k now pairs
// level k with level 15-k (was k and k+8). Per-level cost rises steeply with
// resolution (coarse = L1-hit cheap, fine = uniform-random into the full
// 4 MiB table = L2-request heavy). Old pairing gave XCD7 {7,15} (two most
// expensive) and XCD0 {0,8} (two cheapest of their halves); the slowest XCD
// sets kernel time. New pairing equalizes per-XCD cost sums while preserving
// one-table-per-XCD-per-phase L2 residency.
// r4/r7/r8 established: time moves ONLY with request count (4/pt-level is
// the paired-corner floor); MLP and instruction-count changes are null.
// ---------------------------------------------------------------------------
template <bool TO_WS>
__global__ __launch_bounds__(256) void hashgrid_kernel(
    const float* __restrict__ positions,  // [npoints, 3]
    const float* __restrict__ tables,     // [16, 2^19, 2]
    float2* __restrict__ dst,             // TO_WS: tiled ws; else out [npoints][16]
    int npoints)
{
    int nch = (npoints + 255) >> 8;       // 256-point chunks
    int b = blockIdx.x;
    int L, chunk;
    if (TO_WS) {
        int xcd = b & 7;
        int j = b >> 3;                   // [0, 2*nch)
        L = (j >= nch) ? (15 - xcd) : xcd;   // balanced pairing {k, 15-k}
        chunk = (j >= nch) ? (j - nch) : j;
    } else {
        L = b / nch;
        chunk = b - L * nch;
    }
    int p = (chunk << 8) + threadIdx.x;
    if (p >= npoints) return;

    float px = (positions[3 * p + 0] + 1.0f) * 0.5f;
    float py = (positions[3 * p + 1] + 1.0f) * 0.5f;
    float pz = (positions[3 * p + 2] + 1.0f) * 0.5f;

    float rm1 = (float)(c_res[L] - 1);
    float sx = px * rm1, sy = py * rm1, sz = pz * rm1;
    float bx = floorf(sx), by = floorf(sy), bz = floorf(sz);
    float fx = sx - bx, fy = sy - by, fz = sz - bz;

    unsigned ix = (unsigned)(int)bx;
    unsigned iy = (unsigned)(int)by;
    unsigned iz = (unsigned)(int)bz;

    unsigned s00 = ix + iy * P2 + iz * P3;
    // pair k covers corners (x=0, x=1) at (dy,dz) = (0,0),(1,0),(0,1),(1,1)
    unsigned hl0 = s00 & HMASK;
    unsigned hl1 = (s00 + P2) & HMASK;
    unsigned hl2 = (s00 + P3) & HMASK;
    unsigned hl3 = (s00 + P2 + P3) & HMASK;

    const float* tabf = tables + (size_t)L * (2u * HSIZE);

    unsigned w0 = (hl0 == HMASK) ? 1u : 0u;
    unsigned w1 = (hl1 == HMASK) ? 1u : 0u;
    unsigned w2 = (hl2 == HMASK) ? 1u : 0u;
    unsigned w3 = (hl3 == HMASK) ? 1u : 0u;

    // 16B paired loads: entries {h-w, h-w+1}. All 4 issued back-to-back.
    nf4 g0 = *(const nf4*)(tabf + 2u * (hl0 - w0));
    nf4 g1 = *(const nf4*)(tabf + 2u * (hl1 - w1));
    nf4 g2 = *(const nf4*)(tabf + 2u * (hl2 - w2));
    nf4 g3 = *(const nf4*)(tabf + 2u * (hl3 - w3));
    asm volatile("" :: "v"(g0), "v"(g1), "v"(g2), "v"(g3));

    float2 t0 = ((const float2*)tabf)[0];         // wave-uniform wrap partner

    // lo corner = entry h, hi corner = entry (h+1)&HMASK
    float l0x = w0 ? g0.z : g0.x, l0y = w0 ? g0.w : g0.y;
    float h0x = w0 ? t0.x : g0.z, h0y = w0 ? t0.y : g0.w;
    float l1x = w1 ? g1.z : g1.x, l1y = w1 ? g1.w : g1.y;
    float h1x = w1 ? t0.x : g1.z, h1y = w1 ? t0.y : g1.w;
    float l2x = w2 ? g2.z : g2.x, l2y = w2 ? g2.w : g2.y;
    float h2x = w2 ? t0.x : g2.z, h2y = w2 ? t0.y : g2.w;
    float l3x = w3 ? g3.z : g3.x, l3y = w3 ? g3.w : g3.y;
    float h3x = w3 ? t0.x : g3.z, h3y = w3 ? t0.y : g3.w;

    float wx0 = 1.0f - fx, wy0 = 1.0f - fy, wz0 = 1.0f - fz;
    float c0 = wy0 * wz0;   // (dy,dz)=(0,0)
    float c1 = fy * wz0;    // (1,0)
    float c2 = wy0 * fz;    // (0,1)
    float c3 = fy * fz;     // (1,1)

    float o0 = c0 * (wx0 * l0x + fx * h0x)
             + c1 * (wx0 * l1x + fx * h1x)
             + c2 * (wx0 * l2x + fx * h2x)
             + c3 * (wx0 * l3x + fx * h3x);
    float o1 = c0 * (wx0 * l0y + fx * h0y)
             + c1 * (wx0 * l1y + fx * h1y)
             + c2 * (wx0 * l2y + fx * h2y)
             + c3 * (wx0 * l3y + fx * h3y);

    if (TO_WS) {
        // tiled ws: f2 index = ((p>>8)*16 + L)*256 + (p&255); coalesced, nt.
        nf2 v = {o0, o1};
        __builtin_nontemporal_store(
            v, (nf2*)dst + ((size_t)chunk * NLEVELS + L) * 256 + threadIdx.x);
    } else {
        dst[(size_t)p * NLEVELS + L] = make_float2(o0, o1);
    }
}

// ---------------------------------------------------------------------------
// Kernel B (r11 = r7): tile transpose, 256-pt tiles, 8 concurrent nt loads,
// parity-interleaved LDS rows, nt out stores. Real cost ~55 us (streaming).
// ---------------------------------------------------------------------------
__global__ __launch_bounds__(256) void transpose_kernel(
    const nf4* __restrict__ ws4,
    nf4* __restrict__ out4,
    int npoints)
{
    __shared__ float2 lds[256][NLEVELS + 1];
    int c = blockIdx.x;
    int t = threadIdx.x;
    size_t base = (size_t)c * 2048;   // 2048 x 16B per tile

    nf4 v0 = __builtin_nontemporal_load(&ws4[base + 0 * 256 + t]);
    nf4 v1 = __builtin_nontemporal_load(&ws4[base + 1 * 256 + t]);
    nf4 v2 = __builtin_nontemporal_load(&ws4[base + 2 * 256 + t]);
    nf4 v3 = __builtin_nontemporal_load(&ws4[base + 3 * 256 + t]);
    nf4 v4 = __builtin_nontemporal_load(&ws4[base + 4 * 256 + t]);
    nf4 v5 = __builtin_nontemporal_load(&ws4[base + 5 * 256 + t]);
    nf4 v6 = __builtin_nontemporal_load(&ws4[base + 6 * 256 + t]);
    nf4 v7 = __builtin_nontemporal_load(&ws4[base + 7 * 256 + t]);
    asm volatile("" :: "v"(v0), "v"(v1), "v"(v2), "v"(v3),
                       "v"(v4), "v"(v5), "v"(v6), "v"(v7));

    nf4 vv[8] = {v0, v1, v2, v3, v4, v5, v6, v7};
#pragma unroll
    for (int k = 0; k < 8; ++k) {
        int i = (k << 8) + t;                 // 16B covers f2 {2i, 2i+1}
        int L = i >> 7;                       // level
        int m = i & 127;                      // pts 2m, 2m+1
        lds[m][L]       = make_float2(vv[k].x, vv[k].y);   // row(2m)   = m
        lds[m + 128][L] = make_float2(vv[k].z, vv[k].w);   // row(2m+1) = m+128
    }
    __syncthreads();

#pragma unroll
    for (int k = 0; k < 8; ++k) {
        int i = (k << 8) + t;
        int pp = i >> 3;                      // point within tile
        int q = i & 7;                        // level pair
        int r = (pp >> 1) | ((pp & 1) << 7);  // physical row of point pp
        float2 a = lds[r][2 * q];
        float2 bb = lds[r][2 * q + 1];
        nf4 v = {a.x, a.y, bb.x, bb.y};
        __builtin_nontemporal_store(v, &out4[base + i]);
    }
}

extern "C" void kernel_launch(void* const* d_in, const int* in_sizes, int n_in,
                              void* d_out, int out_size, void* d_ws, size_t ws_size,
                              hipStream_t stream) {
    const float* positions = (const float*)d_in[0];
    const float* tables = (const float*)d_in[1];
    int npoints = in_sizes[0] / 3;                    // 1,048,576
    int nch = (npoints + 255) >> 8;
    int blocks = NLEVELS * nch;                       // 65,536

    size_t ws_needed = (size_t)NLEVELS * npoints * sizeof(float2);  // 128 MiB
    if (ws_size >= ws_needed && (npoints & 255) == 0) {
        float2* ws = (float2*)d_ws;
        hashgrid_kernel<true><<<blocks, 256, 0, stream>>>(positions, tables, ws, npoints);
        transpose_kernel<<<npoints / 256, 256, 0, stream>>>((const nf4*)ws,
                                                            (nf4*)d_out, npoints);
    } else {
        hashgrid_kernel<false><<<blocks, 256, 0, stream>>>(positions, tables,
                                                           (float2*)d_out, npoints);
    }
}